// Round 6
// baseline (189.921 us; speedup 1.0000x reference)
//
#include <hip/hip_runtime.h>
#include <math.h>

#define D 2048
#define EPS_COS 1e-8f
#define EPS_DEN 1e-6f
#define INV_TEMP 10.0f
#define TPB 256
#define WPB 4                   // waves per block
#define RPW 4                   // rows per wave (pipelined)
// nblocks = n / (WPB*RPW) = 16384/16 = 1024

// pos_pair: reference declares int64 but JAX x64-off makes it int32.
// Hedge: accept int32 reading iff plausible (in range, i != j), else int64.
__device__ __forceinline__ void get_ij(const int* __restrict__ p, int n,
                                       int& i, int& j) {
    int i32 = p[0], j32 = p[1];
    if (i32 >= 0 && i32 < n && j32 >= 0 && j32 < n && i32 != j32) {
        i = i32; j = j32; return;
    }
    const long long* p64 = (const long long*)p;
    i = (int)p64[0]; j = (int)p64[1];
}

// Kernel 1: 4 contiguous rows per wave, software-pipelined (prefetch row t+1
// during row t's reduce), xi in registers loaded once per wave. 1024 blocks
// (4/CU) instead of 4096 — less block churn, loads always in flight.
__global__ __launch_bounds__(TPB)
void e_kernel(const float* __restrict__ x, const int* __restrict__ pos,
              float* __restrict__ part, float* __restrict__ nom, int n) {
    int i, j;
    get_ij(pos, n, i, j);
    const int lane  = threadIdx.x & 63;
    const int wave  = threadIdx.x >> 6;
    const int gwave = blockIdx.x * WPB + wave;
    const int row0  = gwave * RPW;

    const float4* __restrict__ xi = (const float4*)(x + (size_t)i * D);

    // issue xi + row0 loads together (16 float4 in flight before any math)
    float4 b[8], a[2][8];
    const float4* __restrict__ p0 = (const float4*)(x + (size_t)row0 * D);
#pragma unroll
    for (int w = 0; w < 8; ++w) a[0][w] = p0[lane + w * 64];
#pragma unroll
    for (int w = 0; w < 8; ++w) b[w] = xi[lane + w * 64];

    float sqi = 0.f;
#pragma unroll
    for (int w = 0; w < 8; ++w)
        sqi = fmaf(b[w].x, b[w].x, fmaf(b[w].y, b[w].y,
              fmaf(b[w].z, b[w].z, fmaf(b[w].w, b[w].w, sqi))));
#pragma unroll
    for (int off = 32; off; off >>= 1) sqi += __shfl_down(sqi, off);
    const float ni = fmaxf(sqrtf(sqi), EPS_COS);   // valid in lane 0

    float den_local = 0.f, ej = 0.f;               // lane-0 accumulators

#pragma unroll
    for (int r = 0; r < RPW; ++r) {
        // prefetch next row while this row reduces
        if (r + 1 < RPW) {
            const float4* __restrict__ pn =
                (const float4*)(x + (size_t)(row0 + r + 1) * D);
#pragma unroll
            for (int w = 0; w < 8; ++w) a[(r + 1) & 1][w] = pn[lane + w * 64];
        }
        float dot = 0.f, sq = 0.f;
#pragma unroll
        for (int w = 0; w < 8; ++w) {
            float4 c = a[r & 1][w];
            dot = fmaf(c.x, b[w].x, fmaf(c.y, b[w].y,
                  fmaf(c.z, b[w].z, fmaf(c.w, b[w].w, dot))));
            sq  = fmaf(c.x, c.x, fmaf(c.y, c.y,
                  fmaf(c.z, c.z, fmaf(c.w, c.w, sq))));
        }
#pragma unroll
        for (int off = 32; off; off >>= 1) {
            dot += __shfl_down(dot, off);
            sq  += __shfl_down(sq,  off);
        }
        if (lane == 0) {
            const int row = row0 + r;
            float e = expf(INV_TEMP * dot / (fmaxf(sqrtf(sq), EPS_COS) * ni));
            if (row != i) den_local += e;   // den includes k==j, excludes k==i
            if (row == j) ej = e;
        }
    }

    __shared__ float s_den[WPB];
    if (lane == 0) {
        s_den[wave] = den_local;
        if (ej != 0.f) *nom = ej;           // exactly one wave owns row j
    }
    __syncthreads();
    if (threadIdx.x == 0)
        part[blockIdx.x] = (s_den[0] + s_den[1]) + (s_den[2] + s_den[3]);
}

// Kernel 2: one 256-thread block sums 1024 partials (4 KB) + finishes loss.
__global__ __launch_bounds__(256)
void loss_kernel(const float* __restrict__ part, const float* __restrict__ nom,
                 float* __restrict__ out, int nblk) {
    const int t = threadIdx.x;
    float s = 0.f;
    if (t < nblk / 4) {
        float4 v = ((const float4*)part)[t];
        s = (v.x + v.y) + (v.z + v.w);
    }
#pragma unroll
    for (int off = 32; off; off >>= 1) s += __shfl_down(s, off);

    __shared__ float ls[4];
    if ((t & 63) == 0) ls[t >> 6] = s;
    __syncthreads();

    if (t == 0) {
        float den = (ls[0] + ls[1]) + (ls[2] + ls[3]);
        out[0] = -logf(nom[0] / (den + EPS_DEN));
    }
}

extern "C" void kernel_launch(void* const* d_in, const int* in_sizes, int n_in,
                              void* d_out, int out_size, void* d_ws, size_t ws_size,
                              hipStream_t stream) {
    const float* x    = (const float*)d_in[0];
    const int*   pos  = (const int*)d_in[1];
    float*       out  = (float*)d_out;

    const int n    = in_sizes[0] / D;              // 16384
    const int nblk = n / (WPB * RPW);              // 1024

    float* part = (float*)d_ws;                    // [0..nblk) block partials
    float* nom  = (float*)d_ws + nblk;             // e_j slot

    e_kernel<<<nblk, TPB, 0, stream>>>(x, pos, part, nom, n);
    loss_kernel<<<1, 256, 0, stream>>>(part, nom, out, nblk);
}